// Round 1
// baseline (485.844 us; speedup 1.0000x reference)
//
#include <hip/hip_runtime.h>
#include <hip/hip_bf16.h>

// Problem constants (from reference)
#define BB 64
#define TT 16
#define ROWS (BB*TT)          // 1024
#define ADIM 32
#define HID 1536
#define NCAT 4

// ---------------------------------------------------------------------------
// Kernel 1: build x = concat(a_emb, tau_emb)  -> (ROWS, 3072) in workspace
//   a_emb[row,h] = sum_d actions[row,d] * W1[cat,d,h] + b1[cat,h]
//   tau[0:768]=sin(t*freq_i), tau[768:1536]=cos(t*freq_i)
// ---------------------------------------------------------------------------
__global__ void build_x_kernel(const float* __restrict__ actions,
                               const int* __restrict__ timesteps,
                               const int* __restrict__ cat_ids,
                               const float* __restrict__ W1,
                               const float* __restrict__ b1,
                               float* __restrict__ X) {
    const int row = blockIdx.x;            // 0..1023
    const int b   = row >> 4;
    const int cat = cat_ids[b];
    const float ts = (float)timesteps[b];
    const int tid = threadIdx.x;

    __shared__ float act[ADIM];
    if (tid < ADIM) act[tid] = actions[(size_t)row * ADIM + tid];
    __syncthreads();

    float* Xrow = X + (size_t)row * (2 * HID);
    const float* W1c = W1 + (size_t)cat * ADIM * HID;
    const float* b1c = b1 + (size_t)cat * HID;

    // a_emb: 1536 outputs, 256 threads -> 6 each
    #pragma unroll
    for (int i = 0; i < 6; ++i) {
        const int h = tid + i * 256;
        float acc = b1c[h];
        #pragma unroll
        for (int d = 0; d < ADIM; ++d)
            acc += act[d] * W1c[(size_t)d * HID + h];
        Xrow[h] = acc;
    }

    // tau_emb: 768 sin + 768 cos
    #pragma unroll
    for (int j = 0; j < 3; ++j) {
        const int i = tid + j * 256;
        const float freq = expf(-9.210340371976184f * (float)i / 768.0f);
        const float ang = ts * freq;
        Xrow[HID + i]        = sinf(ang);
        Xrow[HID + 768 + i]  = cosf(ang);
    }
}

// ---------------------------------------------------------------------------
// Kernel 2/3: Y = act(X @ W[cat] + bias[cat])
//   X: (ROWS, K), W: (NCAT, K, HID), bias: (NCAT, HID), Y: (ROWS, HID)
//   One block: 16 rows of one sample (same cat) x 128 output cols.
//   Thread: 2 rows x 4 cols. X tile (16 x 64) staged in LDS.
// ---------------------------------------------------------------------------
template<int K, bool SWISH>
__global__ __launch_bounds__(256) void gemm_cs_kernel(
        const float* __restrict__ X,
        const float* __restrict__ W,
        const float* __restrict__ bias,
        const int* __restrict__ cat_ids,
        float* __restrict__ Y) {
    const int b   = blockIdx.y;                  // sample
    const int cat = cat_ids[b];
    const int c0  = blockIdx.x * 128;
    const int tid = threadIdx.x;
    const int c4  = c0 + (tid & 31) * 4;         // 4 consecutive cols
    const int r2  = (tid >> 5) * 2;              // 2 consecutive rows

    const float* Xb = X + (size_t)b * TT * K;
    const float* Wc = W + (size_t)cat * K * HID;

    float acc[2][4];
    {
        const float4 bv = *reinterpret_cast<const float4*>(bias + (size_t)cat * HID + c4);
        acc[0][0] = bv.x; acc[0][1] = bv.y; acc[0][2] = bv.z; acc[0][3] = bv.w;
        acc[1][0] = bv.x; acc[1][1] = bv.y; acc[1][2] = bv.z; acc[1][3] = bv.w;
    }

    __shared__ float xs[TT][64];

    for (int k0 = 0; k0 < K; k0 += 64) {
        __syncthreads();
        {   // stage X tile: 16 rows x 64 k, one float4 per thread
            const int r  = tid >> 4;
            const int kk = (tid & 15) * 4;
            const float4 xv = *reinterpret_cast<const float4*>(Xb + (size_t)r * K + k0 + kk);
            *reinterpret_cast<float4*>(&xs[r][kk]) = xv;
        }
        __syncthreads();

        #pragma unroll 8
        for (int kk = 0; kk < 64; ++kk) {
            const float4 wv = *reinterpret_cast<const float4*>(Wc + (size_t)(k0 + kk) * HID + c4);
            const float x0 = xs[r2][kk];
            const float x1 = xs[r2 + 1][kk];
            acc[0][0] += x0 * wv.x; acc[0][1] += x0 * wv.y;
            acc[0][2] += x0 * wv.z; acc[0][3] += x0 * wv.w;
            acc[1][0] += x1 * wv.x; acc[1][1] += x1 * wv.y;
            acc[1][2] += x1 * wv.z; acc[1][3] += x1 * wv.w;
        }
    }

    #pragma unroll
    for (int r = 0; r < 2; ++r) {
        float4 res;
        float v0 = acc[r][0], v1 = acc[r][1], v2 = acc[r][2], v3 = acc[r][3];
        if (SWISH) {
            v0 = v0 / (1.0f + expf(-v0));
            v1 = v1 / (1.0f + expf(-v1));
            v2 = v2 / (1.0f + expf(-v2));
            v3 = v3 / (1.0f + expf(-v3));
        }
        res.x = v0; res.y = v1; res.z = v2; res.w = v3;
        *reinterpret_cast<float4*>(Y + (size_t)(b * TT + r2 + r) * HID + c4) = res;
    }
}

// ---------------------------------------------------------------------------
extern "C" void kernel_launch(void* const* d_in, const int* in_sizes, int n_in,
                              void* d_out, int out_size, void* d_ws, size_t ws_size,
                              hipStream_t stream) {
    const float* actions   = (const float*)d_in[0];
    const int*   timesteps = (const int*)d_in[1];
    const int*   cat_ids   = (const int*)d_in[2];
    const float* W1        = (const float*)d_in[3];
    const float* b1        = (const float*)d_in[4];
    const float* W2        = (const float*)d_in[5];
    const float* b2        = (const float*)d_in[6];
    const float* W3        = (const float*)d_in[7];
    const float* b3        = (const float*)d_in[8];
    float* out = (float*)d_out;

    // workspace layout: X (ROWS x 3072) then H (ROWS x 1536), fp32
    float* X = (float*)d_ws;
    float* H = X + (size_t)ROWS * (2 * HID);

    build_x_kernel<<<ROWS, 256, 0, stream>>>(actions, timesteps, cat_ids, W1, b1, X);

    dim3 grid(HID / 128, BB);
    gemm_cs_kernel<2 * HID, true><<<grid, 256, 0, stream>>>(X, W2, b2, cat_ids, H);
    gemm_cs_kernel<HID, false><<<grid, 256, 0, stream>>>(H, W3, b3, cat_ids, out);
}

// Round 2
// 102.827 us; speedup vs baseline: 4.7249x; 4.7249x over previous
//
#include <hip/hip_runtime.h>
#include <hip/hip_bf16.h>

#define BB 64
#define TT 16
#define ROWS 1024
#define ADIM 32
#define HID 1536
#define NCAT 4
#define MT_MAX 20          // max padded m-tiles: worst case sum ceil(cnt_c/4) = 19

typedef __attribute__((ext_vector_type(8))) short bf16x8;
typedef __attribute__((ext_vector_type(4))) float f32x4;

static __device__ __forceinline__ unsigned short f2bf(float f) {
    union { float f; unsigned int u; } v; v.f = f;
    unsigned int u = v.u + 0x7fff + ((v.u >> 16) & 1);   // RNE (weights/acts finite)
    return (unsigned short)(u >> 16);
}

// ---------------------------------------------------------------------------
// prep: group samples by category into padded 4-sample m-tiles.
// msample[m*4+f] = sample id or -1; mcat[m] = category or -1 (inactive tile)
// ---------------------------------------------------------------------------
__global__ void prep_kernel(const int* __restrict__ cat_ids,
                            int* __restrict__ msample, int* __restrict__ mcat) {
    __shared__ int counts[NCAT];
    const int t = threadIdx.x;
    if (t < NCAT) {
        int c = 0;
        for (int s = 0; s < BB; ++s) c += (cat_ids[s] == t);
        counts[t] = c;
    }
    __syncthreads();
    if (t < NCAT) {
        int off = 0;
        for (int c = 0; c < t; ++c) off += (counts[c] + 3) >> 2;
        const int mt = (counts[t] + 3) >> 2;
        int idx = 0;
        for (int s = 0; s < BB; ++s)
            if (cat_ids[s] == t) msample[off * 4 + (idx++)] = s;
        for (; idx < mt * 4; ++idx) msample[off * 4 + idx] = -1;
        for (int m = 0; m < mt; ++m) mcat[off + m] = t;
    }
    __syncthreads();
    if (t == 0) {
        int tot = 0;
        for (int c = 0; c < NCAT; ++c) tot += (counts[c] + 3) >> 2;
        for (int m = tot; m < MT_MAX; ++m) mcat[m] = -1;
    }
}

// ---------------------------------------------------------------------------
// build_x: X[row][0:1536] = actions @ W1[cat] + b1[cat]; X[row][1536:3072] = PE
// X stored bf16, stride 3072. blockIdx.x = sample; blockIdx.y: 0..5 a_emb strip, 6 = PE
// ---------------------------------------------------------------------------
__global__ void build_x_kernel(const float* __restrict__ actions,
                               const int* __restrict__ timesteps,
                               const int* __restrict__ cat_ids,
                               const float* __restrict__ W1,
                               const float* __restrict__ b1,
                               unsigned short* __restrict__ X) {
    const int s = blockIdx.x;
    const int part = blockIdx.y;
    const int t = threadIdx.x;
    if (part < 6) {
        const int cat = cat_ids[s];
        const int h = part * 256 + t;
        __shared__ float act[TT][ADIM];
        const float* ab = actions + (size_t)s * TT * ADIM;
        ((float*)act)[t]       = ab[t];
        ((float*)act)[t + 256] = ab[t + 256];
        __syncthreads();
        const float* W1c = W1 + (size_t)cat * ADIM * HID + h;
        float acc[TT];
        #pragma unroll
        for (int r = 0; r < TT; ++r) acc[r] = 0.f;
        #pragma unroll 8
        for (int d = 0; d < ADIM; ++d) {
            const float w = W1c[(size_t)d * HID];
            #pragma unroll
            for (int r = 0; r < TT; ++r) acc[r] += act[r][d] * w;
        }
        const float bias = b1[cat * HID + h];
        #pragma unroll
        for (int r = 0; r < TT; ++r)
            X[(size_t)(s * TT + r) * (2 * HID) + h] = f2bf(acc[r] + bias);
    } else {
        const float ts = (float)timesteps[s];
        #pragma unroll
        for (int j = 0; j < 6; ++j) {
            const int i = j * 256 + t;                 // 0..1535
            const int ii = (i < 768) ? i : i - 768;
            const float freq = expf(-9.210340371976184f * (float)ii * (1.0f / 768.0f));
            const float ang = ts * freq;
            const float v = (i < 768) ? sinf(ang) : cosf(ang);
            const unsigned short bv = f2bf(v);
            for (int r = 0; r < TT; ++r)
                X[(size_t)(s * TT + r) * (2 * HID) + HID + i] = bv;
        }
    }
}

// ---------------------------------------------------------------------------
// gemm_part: P[ks] += Xtile @ W[cat] for one 64-row x 64-col tile, K-range ks.
// 1 wave per block. A: bf16 rows of X (16B/lane). B: fp32 W strided dword loads
// + in-register cvt. MFMA 16x16x32 bf16. Partials fp32 to P[ks][row][col].
// ---------------------------------------------------------------------------
template<int K, int S>
__global__ __launch_bounds__(64) void gemm_part_kernel(
        const unsigned short* __restrict__ X,   // [ROWS][K] bf16
        const float* __restrict__ W,            // [NCAT][K][HID] fp32
        const int* __restrict__ msample,
        const int* __restrict__ mcat,
        float* __restrict__ P) {                // [S][ROWS][HID] fp32
    const int m = blockIdx.y;
    const int cat = mcat[m];
    if (cat < 0) return;
    const int n0 = blockIdx.x * 64;
    const int ks = blockIdx.z;
    constexpr int KP = K / S;
    const int k0 = ks * KP;
    const int lane = threadIdx.x;
    const int col = lane & 15;                  // n within 16-col frag; also A row
    const int g = lane >> 4;                    // k-group

    int sidx[4];
    #pragma unroll
    for (int f = 0; f < 4; ++f) sidx[f] = msample[m * 4 + f];

    const unsigned short* arow[4];
    #pragma unroll
    for (int f = 0; f < 4; ++f) {
        const int s = sidx[f] < 0 ? 0 : sidx[f];
        arow[f] = X + (size_t)(s * TT + col) * K + k0 + g * 8;
    }
    const float* wbase = W + ((size_t)cat * K + k0 + g * 8) * HID + n0 + col;

    f32x4 acc[4][4];
    #pragma unroll
    for (int f = 0; f < 4; ++f)
        #pragma unroll
        for (int c = 0; c < 4; ++c) acc[f][c] = f32x4{0.f, 0.f, 0.f, 0.f};

    for (int kk = 0; kk < KP; kk += 32) {
        bf16x8 a[4];
        #pragma unroll
        for (int f = 0; f < 4; ++f)
            a[f] = *(const bf16x8*)(arow[f] + kk);
        const float* wp = wbase + (size_t)kk * HID;
        #pragma unroll
        for (int c = 0; c < 4; ++c) {
            bf16x8 b;
            #pragma unroll
            for (int j = 0; j < 8; ++j) {
                const float w = wp[(size_t)j * HID + c * 16];
                b[j] = (short)f2bf(w);
            }
            #pragma unroll
            for (int f = 0; f < 4; ++f)
                acc[f][c] = __builtin_amdgcn_mfma_f32_16x16x32_bf16(a[f], b, acc[f][c], 0, 0, 0);
        }
    }

    #pragma unroll
    for (int f = 0; f < 4; ++f) {
        if (sidx[f] < 0) continue;
        #pragma unroll
        for (int c = 0; c < 4; ++c) {
            #pragma unroll
            for (int r = 0; r < 4; ++r) {
                const int row = sidx[f] * TT + g * 4 + r;
                P[((size_t)ks * ROWS + row) * HID + n0 + c * 16 + col] = acc[f][c][r];
            }
        }
    }
}

// ---------------------------------------------------------------------------
// finish: out = [swish](sum_s P[s] + bias[cat]), fp32->bf16 or fp32
// ---------------------------------------------------------------------------
template<int S, bool DOSWISH, bool BF16OUT>
__global__ void finish_kernel(const float* __restrict__ P,
                              const float* __restrict__ bias,
                              const int* __restrict__ cat_ids,
                              void* __restrict__ out) {
    const int idx = blockIdx.x * 256 + threadIdx.x;  // one float4 per thread
    const int i4 = idx * 4;
    const int row = i4 / HID;
    const int colb = i4 - row * HID;
    const int cat = cat_ids[row >> 4];
    float4 v = *(const float4*)(P + i4);
    #pragma unroll
    for (int s2 = 1; s2 < S; ++s2) {
        const float4 p = *(const float4*)(P + (size_t)s2 * ROWS * HID + i4);
        v.x += p.x; v.y += p.y; v.z += p.z; v.w += p.w;
    }
    const float4 bv = *(const float4*)(bias + (size_t)cat * HID + colb);
    v.x += bv.x; v.y += bv.y; v.z += bv.z; v.w += bv.w;
    if (DOSWISH) {
        v.x = v.x / (1.f + __expf(-v.x));
        v.y = v.y / (1.f + __expf(-v.y));
        v.z = v.z / (1.f + __expf(-v.z));
        v.w = v.w / (1.f + __expf(-v.w));
    }
    if (BF16OUT) {
        uint2 u;
        u.x = (unsigned)f2bf(v.x) | ((unsigned)f2bf(v.y) << 16);
        u.y = (unsigned)f2bf(v.z) | ((unsigned)f2bf(v.w) << 16);
        *(uint2*)((unsigned short*)out + i4) = u;
    } else {
        *(float4*)((float*)out + i4) = v;
    }
}

// ---------------------------------------------------------------------------
extern "C" void kernel_launch(void* const* d_in, const int* in_sizes, int n_in,
                              void* d_out, int out_size, void* d_ws, size_t ws_size,
                              hipStream_t stream) {
    const float* actions   = (const float*)d_in[0];
    const int*   timesteps = (const int*)d_in[1];
    const int*   cat_ids   = (const int*)d_in[2];
    const float* W1        = (const float*)d_in[3];
    const float* b1        = (const float*)d_in[4];
    const float* W2        = (const float*)d_in[5];
    const float* b2        = (const float*)d_in[6];
    const float* W3        = (const float*)d_in[7];
    const float* b3        = (const float*)d_in[8];

    char* ws = (char*)d_ws;
    unsigned short* X = (unsigned short*)ws;                 // 1024*3072*2 = 6,291,456 B
    unsigned short* H = (unsigned short*)(ws + 6291456);     // 1024*1536*2 = 3,145,728 B
    float* P          = (float*)(ws + 9437184);              // 4*1024*1536*4 = 25,165,824 B
    int* msample      = (int*)(ws + 34603008);               // 80 ints
    int* mcat         = msample + MT_MAX * 4;                // 20 ints

    prep_kernel<<<1, 64, 0, stream>>>(cat_ids, msample, mcat);
    build_x_kernel<<<dim3(BB, 7), 256, 0, stream>>>(actions, timesteps, cat_ids, W1, b1, X);

    gemm_part_kernel<2 * HID, 4><<<dim3(HID / 64, MT_MAX, 4), 64, 0, stream>>>(
        X, W2, msample, mcat, P);
    finish_kernel<4, true, true><<<ROWS * HID / 4 / 256, 256, 0, stream>>>(
        P, b2, cat_ids, H);

    gemm_part_kernel<HID, 4><<<dim3(HID / 64, MT_MAX, 4), 64, 0, stream>>>(
        H, W3, msample, mcat, P);
    finish_kernel<4, false, false><<<ROWS * HID / 4 / 256, 256, 0, stream>>>(
        P, b3, cat_ids, d_out);
}